// Round 7
// baseline (603.650 us; speedup 1.0000x reference)
//
#include <hip/hip_runtime.h>
#include <hip/hip_bf16.h>
#include <math.h>

typedef short short8 __attribute__((ext_vector_type(8)));
typedef float f32x4  __attribute__((ext_vector_type(4)));

#define B_ROWS 8192
#define IN_DIM 1024
#define HID_DIM 1024
#define OUT_DIM 256
#define M_DIM 1280   // HID + OUT
#define P_DIM 2304   // IN + M
#define TBLK 128
#define NBLK (M_DIM / TBLK)  // 10
#define SEQ_WAVES 4
#define USLICE (TBLK / SEQ_WAVES)  // 32

// ws layout: XH bf16[8192][2304] (cols 0..1023 = x, 1024.. = h), then Pre f32[8192][128]
#define XH_OFF 0
#define PRE_OFF (B_ROWS * (size_t)P_DIM * 2)   // 37,748,736 B; total 41,943,040 B

__device__ __forceinline__ short f2bf(float x)
{
    __hip_bfloat16 h = __float2bfloat16(x);
    return *(short*)&h;
}

// ---------------- x (f32) -> XH[:, 0:1024] (bf16) ---------------------------
__global__ __launch_bounds__(256)
void convert_x(const float* __restrict__ x, short* __restrict__ XH)
{
    int idx = blockIdx.x * 256 + threadIdx.x;      // 8192*128 threads, 8 elems each
    int r  = idx >> 7;
    int c8 = (idx & 127) << 3;
    const float* src = x + (size_t)r * IN_DIM + c8;
    float4 a0 = *(const float4*)src;
    float4 a1 = *(const float4*)(src + 4);
    short8 s;
    s[0] = f2bf(a0.x); s[1] = f2bf(a0.y); s[2] = f2bf(a0.z); s[3] = f2bf(a0.w);
    s[4] = f2bf(a1.x); s[5] = f2bf(a1.y); s[6] = f2bf(a1.z); s[7] = f2bf(a1.w);
    *(short8*)(XH + (size_t)r * P_DIM + c8) = s;
}

// ---------------- left-looking panel GEMM -----------------------------------
// Pre[m][n] = sum_{k<Kj} XH[m][k] * W[j0+n][k]  + bias[j0+n]
// Tile 64x64, 4 waves (2x2), wave = 32x32 out (2x2 fragments of 16x16).
#define LDP 40   // LDS row stride in shorts (80 B, 16B-aligned, bank-friendly)

__global__ __launch_bounds__(256)
void gemm_xh(const short* __restrict__ XH, const float* __restrict__ W,
             const float* __restrict__ bias, float* __restrict__ Pre,
             int j0, int Kj)
{
    __shared__ short As[64 * LDP];
    __shared__ short Bs[64 * LDP];
    const int tid  = threadIdx.x;
    const int lane = tid & 63;
    const int wid  = tid >> 6;
    const int wr   = wid >> 1;          // 0..1 (32-row band)
    const int wc   = wid & 1;           // 0..1 (32-col band)
    const int bm   = blockIdx.x * 64;   // batch-row tile
    const int bnB  = blockIdx.y * 64;   // output-col tile (0 or 64)

    f32x4 acc[2][2];
#pragma unroll
    for (int m = 0; m < 2; ++m)
#pragma unroll
        for (int n = 0; n < 2; ++n)
            acc[m][n] = (f32x4){0.f, 0.f, 0.f, 0.f};

    const int rl = lane & 15;
    const int kq = (lane >> 4) * 8;
    const int srow = tid >> 2;          // 0..63
    const int sko  = (tid & 3) << 3;    // 0,8,16,24

    for (int k0 = 0; k0 < Kj; k0 += 32) {
        __syncthreads();
        // stage A (bf16 passthrough) and B (f32 -> bf16)
        *(short8*)&As[srow * LDP + sko] =
            *(const short8*)(XH + (size_t)(bm + srow) * P_DIM + k0 + sko);
        const float* gb = W + (size_t)(j0 + bnB + srow) * P_DIM + k0 + sko;
        float4 b0 = *(const float4*)gb;
        float4 b1 = *(const float4*)(gb + 4);
        short8 sb;
        sb[0] = f2bf(b0.x); sb[1] = f2bf(b0.y); sb[2] = f2bf(b0.z); sb[3] = f2bf(b0.w);
        sb[4] = f2bf(b1.x); sb[5] = f2bf(b1.y); sb[6] = f2bf(b1.z); sb[7] = f2bf(b1.w);
        *(short8*)&Bs[srow * LDP + sko] = sb;
        __syncthreads();

        short8 af[2], bfr[2];
#pragma unroll
        for (int m = 0; m < 2; ++m)
            af[m] = *(const short8*)&As[(wr * 32 + m * 16 + rl) * LDP + kq];
#pragma unroll
        for (int n = 0; n < 2; ++n)
            bfr[n] = *(const short8*)&Bs[(wc * 32 + n * 16 + rl) * LDP + kq];
#pragma unroll
        for (int m = 0; m < 2; ++m)
#pragma unroll
            for (int n = 0; n < 2; ++n)
                acc[m][n] = __builtin_amdgcn_mfma_f32_16x16x32_bf16(
                    af[m], bfr[n], acc[m][n], 0, 0, 0);
    }

    const int rq = (lane >> 4) * 4;
#pragma unroll
    for (int m = 0; m < 2; ++m) {
#pragma unroll
        for (int n = 0; n < 2; ++n) {
            int row = bm + wr * 32 + m * 16 + rq;
            int col = bnB + wc * 32 + n * 16 + rl;     // 0..127
            float bv = bias[j0 + col];
            float* cp = Pre + (size_t)row * TBLK + col;
            f32x4 v = acc[m][n];
#pragma unroll
            for (int r = 0; r < 4; ++r)
                cp[(size_t)r * TBLK] = v[r] + bv;
        }
    }
}

// fast tanh: (e^{2x}-1)/(e^{2x}+1) with hw exp + hw rcp. |err| ~1e-6.
__device__ __forceinline__ float tanh_fast(float x)
{
    x = fminf(fmaxf(x, -15.f), 15.f);
    float e = __expf(2.f * x);
    return (e - 1.f) * __builtin_amdgcn_rcpf(e + 1.f);
}

// -------- within-block sequential recurrence, 4-wave u-partitioned ----------
// Reads Pre (f32, ld=128); writes h (bf16) into XH[:, 1024+j0 ..]; for the
// output region (j0 >= 1024) also writes sigmoid(h) to out.
__global__ __launch_bounds__(256, 1)
void seq_block(const float* __restrict__ Pre, const float* __restrict__ W,
               short* __restrict__ XH, float* __restrict__ out, int j0)
{
    __shared__ float LW[TBLK][TBLK];   // LW[t][u] = (u>t) ? W[j0+u][IN+j0+t] : 0
    __shared__ float hb[2][64];
    const int tid  = threadIdx.x;
    const int lane = tid & 63;
    const int w    = tid >> 6;
    const int row  = blockIdx.x * 64 + lane;

    {
        const int u  = tid & 127;
        const int th = tid >> 7;
        for (int it = 0; it < 16; ++it) {
            int t4 = (it * 2 + th) * 4;
            float4 v = *(const float4*)(W + (size_t)(j0 + u) * P_DIM + (IN_DIM + j0 + t4));
            LW[t4 + 0][u] = (u > t4 + 0) ? v.x : 0.f;
            LW[t4 + 1][u] = (u > t4 + 1) ? v.y : 0.f;
            LW[t4 + 2][u] = (u > t4 + 2) ? v.z : 0.f;
            LW[t4 + 3][u] = (u > t4 + 3) ? v.w : 0.f;
        }
    }

    float acc[USLICE];
    const float* Sp = Pre + (size_t)row * TBLK + w * USLICE;
#pragma unroll
    for (int q = 0; q < USLICE / 4; ++q) {
        float4 v = *(const float4*)(Sp + q * 4);
        acc[q * 4 + 0] = v.x; acc[q * 4 + 1] = v.y;
        acc[q * 4 + 2] = v.z; acc[q * 4 + 3] = v.w;
    }
    __syncthreads();

    for (int g = 0; g < SEQ_WAVES; ++g) {
        const bool own = (w == g);
#pragma unroll
        for (int s = 0; s < 32; ++s) {
            const int t = (g << 5) + s;
            if (own) {
                float h = tanh_fast(acc[s]);
                acc[s] = h;
                hb[s & 1][lane] = h;
            }
            __syncthreads();
            float h = hb[s & 1][lane];
            const float* wrow = &LW[t][w * USLICE];
#pragma unroll
            for (int j = 0; j < USLICE / 4; ++j) {
                float4 wv = *(const float4*)(wrow + j * 4);
                acc[j * 4 + 0] += wv.x * h;
                acc[j * 4 + 1] += wv.y * h;
                acc[j * 4 + 2] += wv.z * h;
                acc[j * 4 + 3] += wv.w * h;
            }
        }
    }

    // write h (bf16) into the XH panel
    short* xo = XH + (size_t)row * P_DIM + IN_DIM + j0 + w * USLICE;
#pragma unroll
    for (int q = 0; q < USLICE / 8; ++q) {
        short8 s;
#pragma unroll
        for (int e = 0; e < 8; ++e) s[e] = f2bf(acc[q * 8 + e]);
        *(short8*)(xo + q * 8) = s;
    }

    // output region: also write sigmoid(h) as f32
    if (j0 >= IN_DIM) {
        float* op = out + (size_t)row * OUT_DIM + (j0 - IN_DIM) + w * USLICE;
#pragma unroll
        for (int q = 0; q < USLICE / 4; ++q) {
            float4 v;
            v.x = 1.f / (1.f + __expf(-acc[q * 4 + 0]));
            v.y = 1.f / (1.f + __expf(-acc[q * 4 + 1]));
            v.z = 1.f / (1.f + __expf(-acc[q * 4 + 2]));
            v.w = 1.f / (1.f + __expf(-acc[q * 4 + 3]));
            *(float4*)(op + q * 4) = v;
        }
    }
}

extern "C" void kernel_launch(void* const* d_in, const int* in_sizes, int n_in,
                              void* d_out, int out_size, void* d_ws, size_t ws_size,
                              hipStream_t stream)
{
    const float* x    = (const float*)d_in[0];   // (8192, 1024)
    const float* W    = (const float*)d_in[1];   // (1280, 2304)
    const float* bias = (const float*)d_in[2];   // (1280,)
    float* out = (float*)d_out;
    short* XH  = (short*)((char*)d_ws + XH_OFF); // bf16 (8192, 2304)
    float* Pre = (float*)((char*)d_ws + PRE_OFF);// f32  (8192, 128)

    // 0) x -> bf16 panel
    convert_x<<<dim3(B_ROWS * IN_DIM / 8 / 256), dim3(256), 0, stream>>>(x, XH);

    // 1) left-looking blocked recurrence
    for (int J = 0; J < NBLK; ++J) {
        int j0 = J * TBLK;
        int Kj = IN_DIM + j0;
        gemm_xh<<<dim3(B_ROWS / 64, TBLK / 64), dim3(256), 0, stream>>>(
            XH, W, bias, Pre, j0, Kj);
        seq_block<<<dim3(B_ROWS / 64), dim3(256), 0, stream>>>(
            Pre, W, XH, out, j0);
    }
}